// Round 1
// baseline (494.905 us; speedup 1.0000x reference)
//
#include <hip/hip_runtime.h>
#include <math.h>

#define N_NODES   500000
#define N_GRAPHS  50000
#define N_EDGES   4000000

// ---- workspace layout (bytes) ----
#define CNT_OFF   0u          // uint32[5,000,000] edge count matrix
#define CHW_OFF   20000000u   // f32[170*64]  champ_table @ W1[0:32]
#define ROW_OFF   20043520u   // f32[10*64]   role_table @ W1[32:40]
#define P1S_OFF   20046080u   // f32[128*64]  BN1 partial sums
#define P1Q_OFF   20078848u   // f32[128*64]  BN1 partial sumsq
#define P2S_OFF   20111616u   // f32[128*32]  BN2 partial sums
#define P2Q_OFF   20128000u   // f32[128*32]  BN2 partial sumsq
#define SC_OFF    20144384u   // f32[192]: scale1[64] shift1[64] scale2[32] shift2[32]
#define Z_OFF     20145152u   // f32[50000*32] pre-BN2 fc1 output
#define ZERO_BYTES 20144384u  // zero cnt + partials (tables are overwritten)

// ---------- tiny table precompute: champW1, roleW1 ----------
__global__ void k_tables(const float* __restrict__ champ, const float* __restrict__ role,
                         const float* __restrict__ W1,
                         float* __restrict__ chW, float* __restrict__ roW) {
    int t = blockIdx.x * blockDim.x + threadIdx.x;
    if (t < 170 * 64) {
        int c = t >> 6, j = t & 63;
        float s = 0.f;
        #pragma unroll
        for (int k = 0; k < 32; k++) s += champ[c * 32 + k] * W1[k * 64 + j];
        chW[t] = s;
    } else if (t < 170 * 64 + 10 * 64) {
        int t2 = t - 170 * 64;
        int r = t2 >> 6, j = t2 & 63;
        float s = 0.f;
        #pragma unroll
        for (int k = 0; k < 8; k++) s += role[r * 8 + k] * W1[(32 + k) * 64 + j];
        roW[t2] = s;
    }
}

// ---------- bin 4M edges into per-graph 10x10 count matrices ----------
__global__ void k_edges(const int* __restrict__ ei, unsigned* __restrict__ cnt) {
    int stride = gridDim.x * blockDim.x;
    for (int e = blockIdx.x * blockDim.x + threadIdx.x; e < N_EDGES; e += stride) {
        unsigned s = (unsigned)ei[e];
        unsigned d = (unsigned)ei[N_EDGES + e];
        unsigned g  = d / 10u;
        unsigned ls = s % 10u;
        unsigned ld = d % 10u;
        atomicAdd(&cnt[g * 100u + ld * 10u + ls], 1u);
    }
}

// ---------- pass1: a1 = Wmat @ hw1 + b1 ; accumulate BN1 stats ----------
__global__ __launch_bounds__(256) void k_pass1(
    const int* __restrict__ x, const unsigned* __restrict__ cnt,
    const float* __restrict__ chW, const float* __restrict__ roW,
    const float* __restrict__ W1, const float* __restrict__ b1,
    float* __restrict__ p1s, float* __restrict__ p1q)
{
    __shared__ unsigned sh_c[4][100];
    __shared__ float    sh_dinv[4][12];
    __shared__ float    sh_w[4][100];
    __shared__ int      sh_x[4][32];

    const int w = threadIdx.x >> 6, lane = threadIdx.x & 63;
    const int g = blockIdx.x * 4 + w;

    if (lane < 30) sh_x[w][lane] = x[g * 30 + lane];
    for (int t = lane; t < 100; t += 64) sh_c[w][t] = cnt[g * 100 + t];
    __syncthreads();

    if (lane < 10) {
        unsigned s = 1u;
        #pragma unroll
        for (int v = 0; v < 10; v++) s += sh_c[w][lane * 10 + v];
        sh_dinv[w][lane] = rsqrtf((float)s);
    }
    __syncthreads();

    for (int t = lane; t < 100; t += 64) {
        int u = t / 10, v = t - u * 10;
        float c = (float)sh_c[w][t] + (u == v ? 1.0f : 0.0f);
        sh_w[w][t] = c * sh_dinv[w][u] * sh_dinv[w][v];
    }

    // hw1[u] = champW1 + roleW1 + team * W1[40]
    const float w1t = W1[40 * 64 + lane];
    float hw[10];
    #pragma unroll
    for (int u = 0; u < 10; u++) {
        int cu = sh_x[w][u * 3 + 0];
        int ru = sh_x[w][u * 3 + 1];
        float tm = (float)sh_x[w][u * 3 + 2];
        hw[u] = chW[cu * 64 + lane] + roW[ru * 64 + lane] + tm * w1t;
    }
    __syncthreads();

    const float b1v = b1[lane];
    float s = 0.f, ss = 0.f;
    #pragma unroll
    for (int u = 0; u < 10; u++) {
        float a = b1v;
        #pragma unroll
        for (int v = 0; v < 10; v++) a += sh_w[w][u * 10 + v] * hw[v];
        s += a; ss += a * a;
    }
    int slot = g & 127;
    atomicAdd(&p1s[slot * 64 + lane], s);
    atomicAdd(&p1q[slot * 64 + lane], ss);
}

// ---------- finalize BN1 -> scale1/shift1 ----------
__global__ void k_fin1(const float* __restrict__ p1s, const float* __restrict__ p1q,
                       const float* __restrict__ gamma, const float* __restrict__ beta,
                       float* __restrict__ sc) {
    int j = threadIdx.x;  // 64
    double s = 0.0, q = 0.0;
    for (int k = 0; k < 128; k++) { s += p1s[k * 64 + j]; q += p1q[k * 64 + j]; }
    double mu = s / (double)N_NODES;
    double var = q / (double)N_NODES - mu * mu;
    float scl = gamma[j] * rsqrtf((float)var + 1e-5f);
    sc[j] = scl;
    sc[64 + j] = beta[j] - (float)mu * scl;
}

// ---------- pass2: recompute a1, BN+relu, layer2, pool, fc1, BN2 stats ----------
__global__ __launch_bounds__(256) void k_pass2(
    const int* __restrict__ x, const unsigned* __restrict__ cnt,
    const float* __restrict__ chW, const float* __restrict__ roW,
    const float* __restrict__ W1, const float* __restrict__ b1,
    const float* __restrict__ sc,
    const float* __restrict__ W2, const float* __restrict__ b2,
    const float* __restrict__ fc1W, const float* __restrict__ fc1b,
    float* __restrict__ z, float* __restrict__ p2s, float* __restrict__ p2q)
{
    __shared__ unsigned sh_c[4][100];
    __shared__ float    sh_dinv[4][12];
    __shared__ float    sh_w[4][100];
    __shared__ int      sh_x[4][32];
    __shared__ float    sh_u2[4][640];
    __shared__ float    sh_g[4][64];
    __shared__ float    sh_fc1[2048];

    const int w = threadIdx.x >> 6, lane = threadIdx.x & 63;
    const int g = blockIdx.x * 4 + w;

    // W2 column for this lane in registers (reused 640x)
    float w2c[64];
    #pragma unroll
    for (int k = 0; k < 64; k++) w2c[k] = W2[k * 64 + lane];

    if (lane < 30) sh_x[w][lane] = x[g * 30 + lane];
    for (int t = lane; t < 100; t += 64) sh_c[w][t] = cnt[g * 100 + t];
    for (int t = threadIdx.x; t < 2048; t += 256) sh_fc1[t] = fc1W[t];
    __syncthreads();

    if (lane < 10) {
        unsigned s = 1u;
        #pragma unroll
        for (int v = 0; v < 10; v++) s += sh_c[w][lane * 10 + v];
        sh_dinv[w][lane] = rsqrtf((float)s);
    }
    __syncthreads();

    for (int t = lane; t < 100; t += 64) {
        int u = t / 10, v = t - u * 10;
        float c = (float)sh_c[w][t] + (u == v ? 1.0f : 0.0f);
        sh_w[w][t] = c * sh_dinv[w][u] * sh_dinv[w][v];
    }

    const float w1t = W1[40 * 64 + lane];
    float hw[10];
    #pragma unroll
    for (int u = 0; u < 10; u++) {
        int cu = sh_x[w][u * 3 + 0];
        int ru = sh_x[w][u * 3 + 1];
        float tm = (float)sh_x[w][u * 3 + 2];
        hw[u] = chW[cu * 64 + lane] + roW[ru * 64 + lane] + tm * w1t;
    }
    __syncthreads();

    // a1 -> h1 (BN1 + relu)
    const float b1v = b1[lane];
    const float sc1 = sc[lane], sf1 = sc[64 + lane];
    float h1[10];
    #pragma unroll
    for (int u = 0; u < 10; u++) {
        float a = b1v;
        #pragma unroll
        for (int v = 0; v < 10; v++) a += sh_w[w][u * 10 + v] * hw[v];
        h1[u] = fmaxf(a * sc1 + sf1, 0.f);
    }
    // u2 = Wmat @ h1 -> LDS
    #pragma unroll
    for (int u = 0; u < 10; u++) {
        float t = 0.f;
        #pragma unroll
        for (int v = 0; v < 10; v++) t += sh_w[w][u * 10 + v] * h1[v];
        sh_u2[w][u * 64 + lane] = t;
    }
    __syncthreads();

    // a2[u][lane] = sum_k u2[u][k] * W2[k][lane] + b2 ; relu ; mean-pool
    const float b2v = b2[lane];
    float gp = 0.f;
    #pragma unroll
    for (int u = 0; u < 10; u++) {
        const float4* up = (const float4*)&sh_u2[w][u * 64];
        float a0 = 0.f, a1a = 0.f, a2a = 0.f, a3 = 0.f;
        #pragma unroll
        for (int k4 = 0; k4 < 16; k4++) {
            float4 q = up[k4];
            a0  += q.x * w2c[4 * k4 + 0];
            a1a += q.y * w2c[4 * k4 + 1];
            a2a += q.z * w2c[4 * k4 + 2];
            a3  += q.w * w2c[4 * k4 + 3];
        }
        gp += fmaxf(a0 + a1a + a2a + a3 + b2v, 0.f);
    }
    gp *= 0.1f;
    sh_g[w][lane] = gp;
    __syncthreads();

    // fc1: z[j'] = sum_j g[j] * fc1W[j][j'] + fc1b[j']   (both half-waves duplicate)
    const int jj = lane & 31;
    const float4* gp4 = (const float4*)&sh_g[w][0];
    float z0 = 0.f, z1 = 0.f, z2 = 0.f, z3 = 0.f;
    #pragma unroll
    for (int j4 = 0; j4 < 16; j4++) {
        float4 q = gp4[j4];
        z0 += q.x * sh_fc1[(4 * j4 + 0) * 32 + jj];
        z1 += q.y * sh_fc1[(4 * j4 + 1) * 32 + jj];
        z2 += q.z * sh_fc1[(4 * j4 + 2) * 32 + jj];
        z3 += q.w * sh_fc1[(4 * j4 + 3) * 32 + jj];
    }
    float zv = z0 + z1 + z2 + z3 + fc1b[jj];
    if (lane < 32) {
        z[g * 32 + jj] = zv;
        int slot = g & 127;
        atomicAdd(&p2s[slot * 32 + jj], zv);
        atomicAdd(&p2q[slot * 32 + jj], zv * zv);
    }
}

// ---------- finalize BN2 -> scale2/shift2 ----------
__global__ void k_fin2(const float* __restrict__ p2s, const float* __restrict__ p2q,
                       const float* __restrict__ gamma, const float* __restrict__ beta,
                       float* __restrict__ sc) {
    int j = threadIdx.x;  // 32
    double s = 0.0, q = 0.0;
    for (int k = 0; k < 128; k++) { s += p2s[k * 32 + j]; q += p2q[k * 32 + j]; }
    double mu = s / (double)N_GRAPHS;
    double var = q / (double)N_GRAPHS - mu * mu;
    float scl = gamma[j] * rsqrtf((float)var + 1e-5f);
    sc[128 + j] = scl;
    sc[160 + j] = beta[j] - (float)mu * scl;
}

// ---------- pass3: BN2 + relu + fc2 + sigmoid ----------
__global__ __launch_bounds__(256) void k_pass3(
    const float* __restrict__ z, const float* __restrict__ sc,
    const float* __restrict__ fc2W, const float* __restrict__ fc2b,
    float* __restrict__ out)
{
    int t = blockIdx.x * blockDim.x + threadIdx.x;
    int g = t >> 5, j = t & 31;
    float y = fmaxf(z[g * 32 + j] * sc[128 + j] + sc[160 + j], 0.f);
    float acc = y * fc2W[j];
    #pragma unroll
    for (int off = 16; off > 0; off >>= 1) acc += __shfl_xor(acc, off, 32);
    if (j == 0) out[g] = 1.0f / (1.0f + __expf(-(acc + fc2b[0])));
}

extern "C" void kernel_launch(void* const* d_in, const int* in_sizes, int n_in,
                              void* d_out, int out_size, void* d_ws, size_t ws_size,
                              hipStream_t stream) {
    const int*   x      = (const int*)d_in[0];
    const int*   ei     = (const int*)d_in[1];
    // d_in[2] = batch (implicit: node/10), unused
    const float* champ  = (const float*)d_in[3];
    const float* role   = (const float*)d_in[4];
    const float* W1     = (const float*)d_in[5];
    const float* b1     = (const float*)d_in[6];
    const float* gamma1 = (const float*)d_in[7];
    const float* beta1  = (const float*)d_in[8];
    const float* W2     = (const float*)d_in[9];
    const float* b2     = (const float*)d_in[10];
    const float* fc1W   = (const float*)d_in[11];
    const float* fc1b   = (const float*)d_in[12];
    const float* gamma2 = (const float*)d_in[13];
    const float* beta2  = (const float*)d_in[14];
    const float* fc2W   = (const float*)d_in[15];
    const float* fc2b   = (const float*)d_in[16];
    float* out = (float*)d_out;

    char* ws = (char*)d_ws;
    unsigned* cnt  = (unsigned*)(ws + CNT_OFF);
    float* chW  = (float*)(ws + CHW_OFF);
    float* roW  = (float*)(ws + ROW_OFF);
    float* p1s  = (float*)(ws + P1S_OFF);
    float* p1q  = (float*)(ws + P1Q_OFF);
    float* p2s  = (float*)(ws + P2S_OFF);
    float* p2q  = (float*)(ws + P2Q_OFF);
    float* scb  = (float*)(ws + SC_OFF);
    float* zbuf = (float*)(ws + Z_OFF);

    hipMemsetAsync(ws, 0, ZERO_BYTES, stream);
    k_tables<<<45, 256, 0, stream>>>(champ, role, W1, chW, roW);
    k_edges<<<2048, 256, 0, stream>>>(ei, cnt);
    k_pass1<<<N_GRAPHS / 4, 256, 0, stream>>>(x, cnt, chW, roW, W1, b1, p1s, p1q);
    k_fin1<<<1, 64, 0, stream>>>(p1s, p1q, gamma1, beta1, scb);
    k_pass2<<<N_GRAPHS / 4, 256, 0, stream>>>(x, cnt, chW, roW, W1, b1, scb,
                                              W2, b2, fc1W, fc1b, zbuf, p2s, p2q);
    k_fin2<<<1, 32, 0, stream>>>(p2s, p2q, gamma2, beta2, scb);
    k_pass3<<<N_GRAPHS / 8, 256, 0, stream>>>(zbuf, scb, fc2W, fc2b, out);
}